// Round 5
// baseline (484.203 us; speedup 1.0000x reference)
//
#include <hip/hip_runtime.h>

// SAMMCodebook.encode, round 8: B-traffic cut. 128 rows x 512 cols per block
// (512 blocks -> codebook re-read traffic halves from 1 GB to 512 MB), 8 waves
// of the proven 64x128 wave tile. Simple depth-1 pipeline (issue A(s+1) regs +
// wave-owned B(s+1) global_load_lds before MFMA; __syncthreads per step) --
// rounds 5b/7 proved schedule-insensitivity, so traffic is the lever.
// r5b-proven XOR swizzles on A and B tiles; in-block exact fp32 fixup.
//
// z[n] = argmin_k (csq[k] - 2<h_n,c_k>). bf16 score error std ~0.1; DELTA=4
// (~40 sigma) margin guarantees the true argmin is among the candidates.

#define D_DIM 1024
#define K_CB  512
#define DELTA 4.0f
#define MAXC_IN 15            // stored "other" candidates; +1 best = 16 slots
#define FULLSCAN 0xFFFFu

typedef __attribute__((ext_vector_type(8))) short short8;
typedef __attribute__((ext_vector_type(4))) float floatx4;

// ws layout
#define WS_CBB  0ull           // 1 MB   cb bf16
#define WS_CSQ  1048576ull     // 2 KB   ||c||^2

typedef const unsigned int __attribute__((address_space(1)))* gaddr_t;
typedef unsigned int __attribute__((address_space(3)))* laddr_t;
static __device__ __forceinline__ void async_copy16(const void* g, void* l) {
    __builtin_amdgcn_global_load_lds((gaddr_t)g, (laddr_t)l, 16, 0, 0);
}

static __device__ __forceinline__ unsigned f2bf(float f) {
    unsigned u = __builtin_bit_cast(unsigned, f);
    return (u + 0x7FFFu + ((u >> 16) & 1u)) >> 16;   // round-nearest-even
}

// ---------------- cb fp32 -> bf16 + csq ----------------
__global__ __launch_bounds__(256)
void prep_kernel(const float* __restrict__ cb, unsigned short* __restrict__ cbb,
                 float* __restrict__ csq) {
    __shared__ float red[4];
    const int k = blockIdx.x, t = threadIdx.x;
    const float4 v = *(const float4*)(cb + (size_t)k * D_DIM + t * 4);
    uint2 u;
    u.x = f2bf(v.x) | (f2bf(v.y) << 16);
    u.y = f2bf(v.z) | (f2bf(v.w) << 16);
    *(uint2*)(cbb + (size_t)k * D_DIM + t * 4) = u;
    float s = v.x * v.x + v.y * v.y + v.z * v.z + v.w * v.w;
    #pragma unroll
    for (int off = 32; off > 0; off >>= 1) s += __shfl_down(s, off, 64);
    if ((t & 63) == 0) red[t >> 6] = s;
    __syncthreads();
    if (t == 0) csq[k] = red[0] + red[1] + red[2] + red[3];
}

// ---------------- coarse: 128x512 per block, 8 waves ----------------
__global__ __launch_bounds__(512, 1)
void coarse_kernel(const float* __restrict__ h,
                   const unsigned short* __restrict__ cbb,
                   const float* __restrict__ csq,
                   const float* __restrict__ cb,
                   int* __restrict__ out) {
    // As = 2 x [128][32] bf16 (16 KB), Bs = 2 x [512][32] bf16 (64 KB) = 80 KB.
    // Post-loop overlay: mval[64][129] f32 | mcol[64][129] i32 | ccnt | clist.
    __shared__ unsigned char smem[81920] __attribute__((aligned(16)));
    unsigned short* As = (unsigned short*)smem;               // shorts
    unsigned short* Bs = (unsigned short*)(smem + 16384);

    const int tid = threadIdx.x;
    const int w = tid >> 6, lane = tid & 63;
    const int l15 = lane & 15, kq = lane >> 4;
    const int cs = w & 3, rh = w >> 2;       // col slice / row half of this wave
    const size_t row0 = (size_t)blockIdx.x * 128;
    const int wc_ = cs * 128;                // wave's 128-col range
    const int rbase = rh * 64;               // wave's 64-row range

    // read-side swizzled 16B-slot offset (r5b-proven), same for A and B
    const int qp8 = (kq ^ ((l15 >> 1) & 3)) * 8;

    // A staging: thread -> row ar=tid>>2 (0..127), logical slot aql=tid&3
    const int ar = tid >> 2, aql = tid & 3;
    const float* gA = h + (row0 + ar) * D_DIM + aql * 8;
    const int awoff = ar * 32 + (aql ^ ((ar >> 1) & 3)) * 8;  // swizzled write

    // B staging, wave-owned 64 rows: inst j covers rows cs*128+rh*64+j*16..+15
    // (lane -> row +(lane>>2), phys slot lane&3). Pre-swizzled global source.
    const int qsrc = (lane & 3) ^ ((lane >> 3) & 3);
    const int brow = cs * 128 + rh * 64 + (lane >> 2);
    const unsigned char* cbb_b = (const unsigned char*)cbb;
    const size_t bsrc_base = ((size_t)brow * D_DIM + qsrc * 8) * 2;   // bytes

    floatx4 acc[4][8];
    #pragma unroll
    for (int i = 0; i < 4; ++i)
        #pragma unroll
        for (int j = 0; j < 8; ++j) acc[i][j] = (floatx4){0.f, 0.f, 0.f, 0.f};

    float4 va0, va1;

#define ISSUE_B(dkn, par) \
    _Pragma("unroll") \
    for (int j = 0; j < 4; ++j) \
        async_copy16(cbb_b + bsrc_base + (size_t)j * (16 * D_DIM * 2) + (size_t)(dkn) * 2, \
                     Bs + (par) * 16384 + (cs * 128 + rh * 64 + j * 16) * 32);

#define PUB_A(par) do { \
    uint4 u; \
    u.x = f2bf(va0.x) | (f2bf(va0.y) << 16); \
    u.y = f2bf(va0.z) | (f2bf(va0.w) << 16); \
    u.z = f2bf(va1.x) | (f2bf(va1.y) << 16); \
    u.w = f2bf(va1.z) | (f2bf(va1.w) << 16); \
    *(uint4*)(As + (par) * 4096 + awoff) = u; \
} while (0)

#define STEP(p, s, LAST) do { \
    if (!(LAST)) { \
        va0 = *(const float4*)(gA + ((s) + 1) * 32); \
        va1 = *(const float4*)(gA + ((s) + 1) * 32 + 4); \
        ISSUE_B(((s) + 1) * 32, (p) ^ 1); \
    } \
    short8 a[4], b[8]; \
    _Pragma("unroll") \
    for (int rt = 0; rt < 4; ++rt) \
        a[rt] = *(const short8*)(As + (p) * 4096 + (rbase + rt * 16 + l15) * 32 + qp8); \
    _Pragma("unroll") \
    for (int ct = 0; ct < 8; ++ct) \
        b[ct] = *(const short8*)(Bs + (p) * 16384 + (wc_ + ct * 16 + l15) * 32 + qp8); \
    __builtin_amdgcn_s_setprio(1); \
    _Pragma("unroll") \
    for (int rt = 0; rt < 4; ++rt) \
        _Pragma("unroll") \
        for (int ct = 0; ct < 8; ++ct) \
            acc[rt][ct] = __builtin_amdgcn_mfma_f32_16x16x32_bf16( \
                a[rt], b[ct], acc[rt][ct], 0, 0, 0); \
    __builtin_amdgcn_s_setprio(0); \
    if (!(LAST)) PUB_A((p) ^ 1); \
    __syncthreads(); \
} while (0)

    // ---- prologue: stage step 0 into buffer 0 ----
    va0 = *(const float4*)(gA);
    va1 = *(const float4*)(gA + 4);
    ISSUE_B(0, 0);
    PUB_A(0);
    __syncthreads();

    for (int s2 = 0; s2 < 16; ++s2) {
        STEP(0, 2 * s2, false);
        STEP(1, 2 * s2 + 1, (s2 == 15));
    }

#undef STEP
#undef PUB_A
#undef ISSUE_B

    // ---- fold: per-lane top-2 per row-reg (cell = 8 cols) ----
    float k1[16], k2[16];
    unsigned cpk[16];
    #pragma unroll
    for (int i = 0; i < 16; ++i) { k1[i] = 3.4e38f; k2[i] = 3.4e38f; cpk[i] = 0; }
    #pragma unroll
    for (int ct = 0; ct < 8; ++ct) {
        const int col = wc_ + ct * 16 + l15;
        const float cq = csq[col];
        #pragma unroll
        for (int rt = 0; rt < 4; ++rt)
            #pragma unroll
            for (int reg = 0; reg < 4; ++reg) {
                const float s = fmaf(-2.0f, acc[rt][ct][reg], cq);
                const int ri = rt * 4 + reg;
                if (s < k1[ri]) {
                    k2[ri] = k1[ri]; k1[ri] = s;
                    cpk[ri] = (cpk[ri] << 16) | (unsigned)col;
                } else if (s < k2[ri]) {
                    k2[ri] = s;
                    cpk[ri] = (cpk[ri] & 0xFFFFu) | ((unsigned)col << 16);
                }
            }
    }

    // ---- merge + decide, one pass per row-half (reuses 64-row machinery) ----
    float* mval = (float*)smem;                        // [64][129]
    int*   mcol = (int*)(smem + 33024);                // [64][129]
    unsigned short* ccnt  = (unsigned short*)(smem + 66048);   // [128]
    unsigned short* clist = (unsigned short*)(smem + 66304);   // [128][16]

    for (int H = 0; H < 2; ++H) {
        __syncthreads();
        if (rh == H) {
            #pragma unroll
            for (int rt = 0; rt < 4; ++rt)
                #pragma unroll
                for (int reg = 0; reg < 4; ++reg) {
                    const int ri = rt * 4 + reg;
                    const int r = rt * 16 + kq * 4 + reg;
                    const int e = (cs * 16 + l15) * 2;
                    mval[r * 129 + e] = k1[ri];
                    mcol[r * 129 + e] = (int)(cpk[ri] & 0xFFFFu);
                    mval[r * 129 + e + 1] = k2[ri];
                    mcol[r * 129 + e + 1] = (int)(cpk[ri] >> 16);
                }
        }
        __syncthreads();
        if (tid < 64) {
            const int r = tid;
            const int gr = H * 64 + r;
            float bv = mval[r * 129]; int bc = mcol[r * 129];
            for (int e = 1; e < 128; ++e) {
                const float v = mval[r * 129 + e];
                const int   c = mcol[r * 129 + e];
                if (v < bv || (v == bv && c < bc)) { bv = v; bc = c; }
            }
            const float thr = bv + DELTA;
            int others = 0;
            for (int e = 0; e < 128; ++e) {
                const float v = mval[r * 129 + e];
                const int   c = mcol[r * 129 + e];
                if (v < thr && c != bc) {
                    if (others < MAXC_IN) clist[gr * 16 + 1 + others] = (unsigned short)c;
                    ++others;
                }
            }
            if (others == 0) {
                out[row0 + gr] = bc;     // unambiguous: approx winner is exact
                ccnt[gr] = 0;
            } else if (others <= MAXC_IN) {
                clist[gr * 16] = (unsigned short)bc;
                ccnt[gr] = (unsigned short)(others + 1);
            } else {
                ccnt[gr] = (unsigned short)FULLSCAN;
            }
        }
    }
    __syncthreads();

    // ---- in-block exact fp32 fixup: one wave per ambiguous row ----
    for (int r = w; r < 128; r += 8) {
        const unsigned cnt = ccnt[r];
        if (cnt == 0) continue;
        const size_t grow = row0 + r;
        const float* hrow = h + grow * D_DIM;
        float4 hv[4];
        #pragma unroll
        for (int j = 0; j < 4; ++j)
            hv[j] = *(const float4*)(hrow + j * 256 + lane * 4);
        float bs = 3.4e38f; int bc = 0x7fffffff;
        const bool full = (cnt == FULLSCAN);
        const int total = full ? K_CB : (int)cnt;
        for (int i = 0; i < total; ++i) {
            const int c = full ? i : (int)clist[r * 16 + i];
            const float* crow = cb + (size_t)c * D_DIM;
            float d = 0.0f;
            #pragma unroll
            for (int j = 0; j < 4; ++j) {
                const float4 cv = *(const float4*)(crow + j * 256 + lane * 4);
                d = fmaf(hv[j].x, cv.x, d);
                d = fmaf(hv[j].y, cv.y, d);
                d = fmaf(hv[j].z, cv.z, d);
                d = fmaf(hv[j].w, cv.w, d);
            }
            #pragma unroll
            for (int off = 32; off > 0; off >>= 1) d += __shfl_down(d, off, 64);
            d = __shfl(d, 0, 64);
            const float sc = fmaf(-2.0f, d, csq[c]);
            if (sc < bs || (sc == bs && c < bc)) { bs = sc; bc = c; }
        }
        if (lane == 0) out[grow] = bc;
    }
}

extern "C" void kernel_launch(void* const* d_in, const int* in_sizes, int n_in,
                              void* d_out, int out_size, void* d_ws, size_t ws_size,
                              hipStream_t stream) {
    const float* h  = (const float*)d_in[0];
    const float* cb = (const float*)d_in[1];
    int* out = (int*)d_out;
    unsigned char* ws = (unsigned char*)d_ws;
    const int nrows = in_sizes[0] / D_DIM;   // 65536

    unsigned short* cbb = (unsigned short*)(ws + WS_CBB);
    float* csq = (float*)(ws + WS_CSQ);

    prep_kernel<<<dim3(K_CB), dim3(256), 0, stream>>>(cb, cbb, csq);
    coarse_kernel<<<dim3(nrows / 128), dim3(512), 0, stream>>>(
        h, cbb, csq, cb, out);
}